// Round 3
// baseline (369.973 us; speedup 1.0000x reference)
//
#include <hip/hip_runtime.h>

// RegionIntegrator: B=4, N_REG=225 (15x15 grid, step 32), C=16, RS=64, H=W=512.
// Gather formulation: each output pixel (y,x) is covered by at most 2x2 regions
//   i in {max(0,(y-32)>>5), min(14, y>>5)}, same for j with x.
// Straight-line: always issue 4 float4 loads (clamped indices duplicate at
// edges -> same-address L1/L2 hits, no extra HBM), weighted sum with {0,1}
// weights in ascending-n order (bit-exact vs reference scatter), divide by
// closed-form count in {1,2,4} (exact power of two).
// Ideal traffic: 236 MB read + 67 MB write ~= 48 us at 6.3 TB/s.

constexpr int CH = 16;
constexpr int HW = 512;

typedef float floatx4 __attribute__((ext_vector_type(4)));  // clang vector: valid for nontemporal builtins

__global__ __launch_bounds__(256) void region_gather_kernel(
    const float* __restrict__ regions, float* __restrict__ out)
{
    // tid layout: b[2] | c[4] | y[9] | xq[7]  (xq = x/4, lane-fastest -> coalesced)
    int tid = blockIdx.x * 256 + threadIdx.x;
    int xq = tid & 127;          // x / 4
    int x  = xq << 2;
    int y  = (tid >> 7) & 511;
    int bc = tid >> 16;          // b*16 + c
    int b  = bc >> 4;
    int c  = bc & 15;

    // covering region-start indices (step=32, RS=64); arithmetic shift handles y<32
    int i0 = max((y - 32) >> 5, 0);
    int i1 = min(y >> 5, 14);
    int j0 = max((x - 32) >> 5, 0);
    int j1 = min(x >> 5, 14);

    int dy0 = y - (i0 << 5), dy1 = y - (i1 << 5);
    int dx0 = x - (j0 << 5), dx1 = x - (j1 << 5);   // multiples of 4 -> aligned float4

    // addr(floats) = (b*3600 + c)*4096 + n*65536 + dy*64 + dx,  n = i*15 + j
    const float* p = regions + (size_t)(b * 3600 + c) * 4096;
    const floatx4 v00 = *(const floatx4*)(p + (size_t)(i0 * 15 + j0) * 65536 + dy0 * 64 + dx0);
    const floatx4 v01 = *(const floatx4*)(p + (size_t)(i0 * 15 + j1) * 65536 + dy0 * 64 + dx1);
    const floatx4 v10 = *(const floatx4*)(p + (size_t)(i1 * 15 + j0) * 65536 + dy1 * 64 + dx0);
    const floatx4 v11 = *(const floatx4*)(p + (size_t)(i1 * 15 + j1) * 65536 + dy1 * 64 + dx1);

    const float fi  = (i1 != i0) ? 1.0f : 0.0f;
    const float fj  = (j1 != j0) ? 1.0f : 0.0f;
    const float fij = fi * fj;
    // count = (1+fi)*(1+fj) in {1,2,4} -> inv is an exact power of two
    const float inv = 1.0f / ((1.0f + fi) * (1.0f + fj));

    floatx4 r = (v00 + fj * v01 + fi * v10 + fij * v11) * inv;

    // write-once output: nontemporal store, skip L2 residency
    __builtin_nontemporal_store(r, reinterpret_cast<floatx4*>(out) + tid);
}

extern "C" void kernel_launch(void* const* d_in, const int* in_sizes, int n_in,
                              void* d_out, int out_size, void* d_ws, size_t ws_size,
                              hipStream_t stream) {
    const float* regions = (const float*)d_in[0];   // (4,225,16,64,64) f32
    // d_in[1] orig_x: unused (shape only). d_in[2] positions: regular grid,
    // folded into closed-form index math. d_in[3..6]: scalars.
    float* out = (float*)d_out;                     // (4,16,512,512) f32

    int total_f4 = 4 * CH * HW * (HW / 4);          // 4,194,304 threads
    region_gather_kernel<<<total_f4 / 256, 256, 0, stream>>>(regions, out);
}